// Round 1
// baseline (72985.358 us; speedup 1.0000x reference)
//
#include <hip/hip_runtime.h>

namespace {
constexpr int B = 128;      // batch
constexpr int D = 80;       // mel dim
constexpr int H = 256;      // hidden
constexpr int PP = 128;     // prenet out
constexpr int TIN = 512;    // encoder steps
constexpr int RSTEPS = 200; // reduced steps
constexpr int RF = 5;       // reduction factor
constexpr int H3 = 3 * H;   // 768
}

// ---------------------------------------------------------------------------
// keys[t,b,k] = sum_h memory[t,b,h] * Wm[h,k]   (one-time per call)
// flattened rows m = t*B + b (M = 65536). Each WG: 32 rows, thread = column k.
__global__ __launch_bounds__(256) void k_keys(const float* __restrict__ mem,
                                              const float* __restrict__ Wm,
                                              float* __restrict__ keys) {
  const int k = threadIdx.x;          // 0..255
  const int m0 = blockIdx.x * 32;     // 2048 blocks
  const float* xb = mem + (size_t)m0 * H;
  float acc[32];
#pragma unroll
  for (int i = 0; i < 32; ++i) acc[i] = 0.f;
  for (int h = 0; h < H; h += 4) {
    const float w0 = Wm[(h + 0) * H + k];
    const float w1 = Wm[(h + 1) * H + k];
    const float w2 = Wm[(h + 2) * H + k];
    const float w3 = Wm[(h + 3) * H + k];
#pragma unroll
    for (int mi = 0; mi < 32; ++mi) {
      const float4 x = *reinterpret_cast<const float4*>(xb + (size_t)mi * H + h);
      acc[mi] += x.x * w0 + x.y * w1 + x.z * w2 + x.w * w3;
    }
  }
#pragma unroll
  for (int mi = 0; mi < 32; ++mi) keys[(size_t)(m0 + mi) * H + k] = acc[mi];
}

// ---------------------------------------------------------------------------
// Repack GRU weight [K,768] (cols: z=0..255, r=256..511, c=512..767) into
// gate-interleaved [K][j*4 + g] (g=0:z,1:r,2:c,3:pad-unused).
__global__ __launch_bounds__(256) void k_pack(const float* __restrict__ W,
                                              float* __restrict__ Wp, int K) {
  const int idx = blockIdx.x * 256 + threadIdx.x;
  if (idx >= K * H3) return;
  const int k = idx / H3;
  const int c = idx % H3;
  const int g = c >> 8;        // 0..2
  const int j = c & 255;
  Wp[(size_t)k * 1024 + j * 4 + g] = W[idx];
}

// ---------------------------------------------------------------------------
// Per-batch-row WG (grid=B): (A) dense output of step t-1 from res1, written
// to 5 output frames; (B) prenet for step t -> pre_T[j][b].
__global__ __launch_bounds__(256) void k1_dense_prenet(
    int t, const float* __restrict__ outs, const float* __restrict__ res1,
    const float* __restrict__ Wo, const float* __restrict__ bo,
    const float* __restrict__ Wp0, const float* __restrict__ bp0,
    const float* __restrict__ Wp1, const float* __restrict__ bp1,
    float* __restrict__ preT, float* __restrict__ dout) {
  const int b = blockIdx.x;
  const int tid = threadIdx.x;
  __shared__ float f[D];
  __shared__ float p0[H];

  if (t > 0 && tid < D) {            // phase A: dense for step t-1
    float acc = bo[tid];
#pragma unroll 4
    for (int k = 0; k < H; ++k) acc += res1[k * B + b] * Wo[k * D + tid];
    const size_t tb = (size_t)(t - 1) * RF;
    for (int i = 0; i < RF; ++i)
      dout[(tb + i) * (size_t)(B * D) + b * D + tid] = acc;
  }
  if (t == RSTEPS) return;           // final call: dense only

  if (tid < D)
    f[tid] = (t == 0) ? 0.f
                      : outs[(size_t)(t * RF - 1) * (B * D) + b * D + tid];
  __syncthreads();
  {                                  // prenet layer 0 (256 outputs)
    float acc = bp0[tid];
#pragma unroll 4
    for (int d0 = 0; d0 < D; ++d0) acc += f[d0] * Wp0[d0 * H + tid];
    p0[tid] = fmaxf(acc, 0.f);
  }
  __syncthreads();
  if (tid < PP) {                    // prenet layer 1 (128 outputs)
    float acc = bp1[tid];
#pragma unroll 4
    for (int k = 0; k < H; ++k) acc += p0[k] * Wp1[k * PP + tid];
    preT[tid * B + b] = fmaxf(acc, 0.f);
  }
}

// ---------------------------------------------------------------------------
// Column-parallel GRU: out[j][b] computed by thread (j=wave-of-WG, b=lane+half).
// x_T[Kx][B], packed Wxp[Kx][1024], h_old_T[H][B], packed Whp[H][1024].
// Optionally res_out = res_in + h_new.
__global__ __launch_bounds__(256) void k_gru(
    const float* __restrict__ xT, int Kx, const float* __restrict__ Wxp,
    const float* __restrict__ hT_old, const float* __restrict__ Whp,
    const float* __restrict__ b3, float* __restrict__ hT_new,
    const float* __restrict__ resIn, float* __restrict__ resOut) {
  const int w = blockIdx.x;                 // 128 WGs
  const int bh = w & 1;
  const int jg = w >> 1;
  const int lane = threadIdx.x & 63;
  const int wave = threadIdx.x >> 6;
  const int j = jg * 4 + wave;              // 0..255 (4 consecutive j per WG)
  const int b = bh * 64 + lane;             // 0..127

  float az = 0.f, ar = 0.f, ac = 0.f;
  const float4* wx = reinterpret_cast<const float4*>(Wxp) + j;
#pragma unroll 4
  for (int k = 0; k < Kx; ++k) {
    const float4 wv = wx[(size_t)k * 256];  // uniform per wave; WG's 4 waves share line
    const float xv = xT[k * B + b];         // coalesced
    az += wv.x * xv; ar += wv.y * xv; ac += wv.z * xv;
  }
  float bz = 0.f, br = 0.f, bc = 0.f;
  const float4* wh = reinterpret_cast<const float4*>(Whp) + j;
#pragma unroll 4
  for (int k = 0; k < H; ++k) {
    const float4 wv = wh[(size_t)k * 256];
    const float hv = hT_old[k * B + b];
    bz += wv.x * hv; br += wv.y * hv; bc += wv.z * hv;
  }
  const float z = 1.f / (1.f + __expf(-(az + bz + b3[j])));
  const float r = 1.f / (1.f + __expf(-(ar + br + b3[H + j])));
  const float carg = ac + r * bc + b3[2 * H + j];
  const float ex = __expf(2.f * carg);
  const float c = 1.f - 2.f / (ex + 1.f);   // tanh
  const float hold = hT_old[j * B + b];
  const float hn = (1.f - z) * hold + z * c;
  hT_new[j * B + b] = hn;
  if (resOut) resOut[j * B + b] = resIn[j * B + b] + hn;
}

// ---------------------------------------------------------------------------
// Per-batch-row WG (grid=B): qW = query@Wq; e_t = v . tanh(keys+qW); softmax;
// context = sum_t alpha_t * memory[t,b,:]; writes alpha to d_out.
__global__ __launch_bounds__(256) void k3_attn(
    int t, const float* __restrict__ queryT, const float* __restrict__ Wq,
    const float* __restrict__ v_att, const float* __restrict__ keys,
    const float* __restrict__ mem, float* __restrict__ ctxT,
    float* __restrict__ alpha_out) {
  const int b = blockIdx.x;
  const int tid = threadIdx.x;
  const int lane = tid & 63;
  const int wave = tid >> 6;
  __shared__ float qk[H];
  __shared__ float vv[H];
  __shared__ float ee[TIN];
  __shared__ float sred[4];
  __shared__ float sbc[2];

  {                                   // qW[b,:] (broadcast query reads, coalesced Wq)
    float acc = 0.f;
#pragma unroll 4
    for (int k = 0; k < H; ++k) acc += queryT[k * B + b] * Wq[k * H + tid];
    qk[tid] = acc;
    vv[tid] = v_att[tid];
  }
  __syncthreads();

  const float* kb = keys + (size_t)b * H;
  for (int tt = wave; tt < TIN; tt += 4) {   // wave-per-t, k in lanes (coalesced)
    const float* kr = kb + (size_t)tt * (B * H);
    float s = 0.f;
#pragma unroll
    for (int i = 0; i < 4; ++i) {
      const int k = lane + i * 64;
      const float x = kr[k] + qk[k];
      const float ex = __expf(2.f * x);
      s += vv[k] * (1.f - 2.f / (ex + 1.f));
    }
#pragma unroll
    for (int m = 1; m < 64; m <<= 1) s += __shfl_xor(s, m);
    if (lane == 0) ee[tt] = s;
  }
  __syncthreads();

  float e0 = ee[tid], e1 = ee[tid + 256];
  float mx = fmaxf(e0, e1);
#pragma unroll
  for (int m = 1; m < 64; m <<= 1) mx = fmaxf(mx, __shfl_xor(mx, m));
  if (lane == 0) sred[wave] = mx;
  __syncthreads();
  if (tid == 0)
    sbc[0] = fmaxf(fmaxf(sred[0], sred[1]), fmaxf(sred[2], sred[3]));
  __syncthreads();
  const float gm = sbc[0];
  e0 = __expf(e0 - gm);
  e1 = __expf(e1 - gm);
  ee[tid] = e0;
  ee[tid + 256] = e1;
  float sm = e0 + e1;
#pragma unroll
  for (int m = 1; m < 64; m <<= 1) sm += __shfl_xor(sm, m);
  if (lane == 0) sred[wave] = sm;
  __syncthreads();
  if (tid == 0) sbc[1] = 1.f / (sred[0] + sred[1] + sred[2] + sred[3]);
  __syncthreads();
  const float inv = sbc[1];

  {                                   // alpha out: [t][b][tin], coalesced
    float* ap = alpha_out + ((size_t)t * B + b) * TIN;
    ap[tid] = e0 * inv;
    ap[tid + 256] = e1 * inv;
  }
  {                                   // context (k = tid lanes, coalesced over memory)
    float acc = 0.f;
    const float* mb = mem + (size_t)b * H + tid;
#pragma unroll 4
    for (int tt = 0; tt < TIN; ++tt) acc += ee[tt] * mb[(size_t)tt * (B * H)];
    ctxT[tid * B + b] = acc * inv;
  }
}

// ---------------------------------------------------------------------------
extern "C" void kernel_launch(void* const* d_in, const int* in_sizes, int n_in,
                              void* d_out, int out_size, void* d_ws,
                              size_t ws_size, hipStream_t stream) {
  const float* outs   = (const float*)d_in[0];
  const float* memory = (const float*)d_in[1];
  const float* Wp0    = (const float*)d_in[2];
  const float* bp0    = (const float*)d_in[3];
  const float* Wp1    = (const float*)d_in[4];
  const float* bp1    = (const float*)d_in[5];
  const float* Wx_att = (const float*)d_in[6];
  const float* Wh_att = (const float*)d_in[7];
  const float* b_att  = (const float*)d_in[8];
  const float* Wq     = (const float*)d_in[9];
  const float* Wm     = (const float*)d_in[10];
  const float* v_att  = (const float*)d_in[11];
  const float* Wx_d0  = (const float*)d_in[12];
  const float* Wh_d0  = (const float*)d_in[13];
  const float* b_d0   = (const float*)d_in[14];
  const float* Wx_d1  = (const float*)d_in[15];
  const float* Wh_d1  = (const float*)d_in[16];
  const float* b_d1   = (const float*)d_in[17];
  const float* Wo     = (const float*)d_in[18];
  const float* bo     = (const float*)d_in[19];
  float* dout = (float*)d_out;
  float* wsf  = (float*)d_ws;

  size_t off = 0;
  float* keys    = wsf + off; off += (size_t)TIN * B * H;  // 16.78M floats
  float* wxp_att = wsf + off; off += (size_t)128 * 1024;
  float* whp_att = wsf + off; off += (size_t)256 * 1024;
  float* wxp_d0  = wsf + off; off += (size_t)512 * 1024;
  float* whp_d0  = wsf + off; off += (size_t)256 * 1024;
  float* wxp_d1  = wsf + off; off += (size_t)256 * 1024;
  float* whp_d1  = wsf + off; off += (size_t)256 * 1024;
  float* xcat[2];
  xcat[0] = wsf + off; off += (size_t)2 * H * B;
  xcat[1] = wsf + off; off += (size_t)2 * H * B;
  float* hd0[2];
  hd0[0] = wsf + off; off += (size_t)H * B;
  hd0[1] = wsf + off; off += (size_t)H * B;
  float* hd1[2];
  hd1[0] = wsf + off; off += (size_t)H * B;
  hd1[1] = wsf + off; off += (size_t)H * B;
  float* preT = wsf + off; off += (size_t)PP * B;
  float* res0 = wsf + off; off += (size_t)H * B;
  float* res1 = wsf + off; off += (size_t)H * B;

  // zero initial hidden states (h_att lives in query half of xcat[0])
  hipMemsetAsync(xcat[0], 0, (size_t)H * B * sizeof(float), stream);
  hipMemsetAsync(hd0[0], 0, (size_t)H * B * sizeof(float), stream);
  hipMemsetAsync(hd1[0], 0, (size_t)H * B * sizeof(float), stream);

  // one-time precompute (re-done each call: deterministic)
  k_keys<<<(TIN * B) / 32, 256, 0, stream>>>(memory, Wm, keys);
  k_pack<<<(128 * H3 + 255) / 256, 256, 0, stream>>>(Wx_att, wxp_att, 128);
  k_pack<<<(256 * H3 + 255) / 256, 256, 0, stream>>>(Wh_att, whp_att, 256);
  k_pack<<<(512 * H3 + 255) / 256, 256, 0, stream>>>(Wx_d0, wxp_d0, 512);
  k_pack<<<(256 * H3 + 255) / 256, 256, 0, stream>>>(Wh_d0, whp_d0, 256);
  k_pack<<<(256 * H3 + 255) / 256, 256, 0, stream>>>(Wx_d1, wxp_d1, 256);
  k_pack<<<(256 * H3 + 255) / 256, 256, 0, stream>>>(Wh_d1, whp_d1, 256);

  float* alpha_out = dout + (size_t)1000 * B * D;  // final_output is 10.24M floats

  for (int t = 0; t < RSTEPS; ++t) {
    const int pi = t & 1, po = 1 - pi;
    // dense(t-1) + prenet(t)
    k1_dense_prenet<<<B, 256, 0, stream>>>(t, outs, res1, Wo, bo, Wp0, bp0,
                                           Wp1, bp1, preT, dout);
    // attention GRU: query = GRU(pre, h_att); h_att' = query
    k_gru<<<B, 256, 0, stream>>>(preT, PP, wxp_att, xcat[pi], whp_att, b_att,
                                 xcat[po], nullptr, nullptr);
    // qW + attention + context (context written into xcat[po] second half)
    k3_attn<<<B, 256, 0, stream>>>(t, xcat[po], Wq, v_att, keys, memory,
                                   xcat[po] + (size_t)H * B, alpha_out);
    // decoder GRU 0: x = [query; context], res0 = query + out0
    k_gru<<<B, 256, 0, stream>>>(xcat[po], 2 * H, wxp_d0, hd0[pi], whp_d0,
                                 b_d0, hd0[po], xcat[po], res0);
    // decoder GRU 1: res1 = res0 + out1
    k_gru<<<B, 256, 0, stream>>>(res0, H, wxp_d1, hd1[pi], whp_d1, b_d1,
                                 hd1[po], res0, res1);
  }
  // final dense for step RSTEPS-1
  k1_dense_prenet<<<B, 256, 0, stream>>>(RSTEPS, outs, res1, Wo, bo, Wp0, bp0,
                                         Wp1, bp1, preT, dout);
}

// Round 2
// 19253.581 us; speedup vs baseline: 3.7907x; 3.7907x over previous
//
#include <hip/hip_runtime.h>

namespace {
constexpr int B = 128;      // batch
constexpr int D = 80;       // mel dim
constexpr int H = 256;      // hidden
constexpr int PP = 128;     // prenet out
constexpr int TIN = 512;    // encoder steps
constexpr int RSTEPS = 200; // reduced steps
constexpr int RF = 5;       // reduction factor
constexpr int H3 = 3 * H;   // 768
}

// ---------------------------------------------------------------------------
// keys[t,b,k] = sum_h memory[t,b,h] * Wm[h,k]   (one-time per call)
__global__ __launch_bounds__(256) void k_keys(const float* __restrict__ mem,
                                              const float* __restrict__ Wm,
                                              float* __restrict__ keys) {
  const int k = threadIdx.x;
  const int m0 = blockIdx.x * 32;
  const float* xb = mem + (size_t)m0 * H;
  float acc[32];
#pragma unroll
  for (int i = 0; i < 32; ++i) acc[i] = 0.f;
  for (int h = 0; h < H; h += 4) {
    const float w0 = Wm[(h + 0) * H + k];
    const float w1 = Wm[(h + 1) * H + k];
    const float w2 = Wm[(h + 2) * H + k];
    const float w3 = Wm[(h + 3) * H + k];
#pragma unroll
    for (int mi = 0; mi < 32; ++mi) {
      const float4 x = *reinterpret_cast<const float4*>(xb + (size_t)mi * H + h);
      acc[mi] += x.x * w0 + x.y * w1 + x.z * w2 + x.w * w3;
    }
  }
#pragma unroll
  for (int mi = 0; mi < 32; ++mi) keys[(size_t)(m0 + mi) * H + k] = acc[mi];
}

// ---------------------------------------------------------------------------
// Repack GRU weight [K,768] into gate-interleaved [K][j*4 + g] (g=0:z,1:r,2:c).
__global__ __launch_bounds__(256) void k_pack(const float* __restrict__ W,
                                              float* __restrict__ Wp, int K) {
  const int idx = blockIdx.x * 256 + threadIdx.x;
  if (idx >= K * H3) return;
  const int k = idx / H3;
  const int c = idx % H3;
  const int g = c >> 8;
  const int j = c & 255;
  Wp[(size_t)k * 1024 + j * 4 + g] = W[idx];
}

// ---------------------------------------------------------------------------
// grid=B, 512 threads. (A) dense of step t-1 (split-K 4-way), (B) prenet (split-K).
__global__ __launch_bounds__(512) void k1_dense_prenet(
    int t, const float* __restrict__ outs, const float* __restrict__ res1,
    const float* __restrict__ Wo, const float* __restrict__ bo,
    const float* __restrict__ Wp0, const float* __restrict__ bp0,
    const float* __restrict__ Wp1, const float* __restrict__ bp1,
    float* __restrict__ preT, float* __restrict__ dout) {
  const int b = blockIdx.x;
  const int tid = threadIdx.x;
  __shared__ float f[D];
  __shared__ float pA[512];
  __shared__ float p0[H];
  __shared__ float pB[512];
  __shared__ float pC[512];

  {                                    // phase A partials: (q, d)
    const int q = tid >> 7, d = tid & 127;
    float acc = 0.f;
    if (t > 0 && d < D) {
      const int k0 = q * 64;
#pragma unroll 4
      for (int i = 0; i < 64; ++i) {
        const int k = k0 + i;
        acc += res1[k * B + b] * Wo[k * D + d];
      }
    }
    pA[q * 128 + d] = acc;
  }
  if (tid < D)
    f[tid] = (t == 0 || t == RSTEPS)
                 ? 0.f
                 : outs[(size_t)(t * RF - 1) * (B * D) + b * D + tid];
  __syncthreads();
  if (t > 0 && tid < D) {
    const float dv = bo[tid] + pA[tid] + pA[128 + tid] + pA[256 + tid] + pA[384 + tid];
    const size_t tb = (size_t)(t - 1) * RF;
    for (int i = 0; i < RF; ++i)
      dout[(tb + i) * (size_t)(B * D) + b * D + tid] = dv;
  }
  if (t == RSTEPS) return;

  {                                    // prenet layer 0: (kh, j) over K=80
    const int kh = tid >> 8, j = tid & 255;
    float acc = 0.f;
    const int k0 = kh * 40, k1e = k0 + 40;
#pragma unroll 4
    for (int k = k0; k < k1e; ++k) acc += f[k] * Wp0[k * H + j];
    pB[kh * 256 + j] = acc;
  }
  __syncthreads();
  if (tid < H) p0[tid] = fmaxf(bp0[tid] + pB[tid] + pB[256 + tid], 0.f);
  __syncthreads();
  {                                    // prenet layer 1: (kq, j) over K=256
    const int kq = tid >> 7, j = tid & 127;
    float acc = 0.f;
    const int k0 = kq * 64;
#pragma unroll 4
    for (int i = 0; i < 64; ++i) {
      const int k = k0 + i;
      acc += p0[k] * Wp1[k * PP + j];
    }
    pC[kq * 128 + j] = acc;
  }
  __syncthreads();
  if (tid < PP)
    preT[tid * B + b] =
        fmaxf(bp1[tid] + pC[tid] + pC[128 + tid] + pC[256 + tid] + pC[384 + tid], 0.f);
}

// ---------------------------------------------------------------------------
// Split-K GRU: grid = (H/2)*2 = 256 blocks, 1024 threads (16 waves).
// Block owns 2 j's x 64 b's; waves split the combined K = Kx + H reduction.
__global__ __launch_bounds__(1024) void k_gru(
    const float* __restrict__ xT, int Kx, const float* __restrict__ Wxp,
    const float* __restrict__ hT_old, const float* __restrict__ Whp,
    const float* __restrict__ b3, float* __restrict__ hT_new,
    const float* __restrict__ resIn, float* __restrict__ resOut) {
  const int blk = blockIdx.x;
  const int bh = blk & 1;
  const int j0 = (blk >> 1) * 2;
  const int tid = threadIdx.x;
  const int lane = tid & 63, w16 = tid >> 6;
  const int b = bh * 64 + lane;

  __shared__ float part[16 * 512];
  __shared__ float red[512];

  const int KT = Kx + H;
  const int KS = KT >> 4;              // KT divisible by 16 for all call sites
  const int k0 = w16 * KS, k1e = k0 + KS;

  float az0 = 0, ar0 = 0, acx0 = 0, ach0 = 0;
  float az1 = 0, ar1 = 0, acx1 = 0, ach1 = 0;

  const int xe = min(k1e, Kx);
#pragma unroll 4
  for (int k = k0; k < xe; ++k) {
    const float4 w0 = *reinterpret_cast<const float4*>(Wxp + (size_t)k * 1024 + j0 * 4);
    const float4 w1 = *reinterpret_cast<const float4*>(Wxp + (size_t)k * 1024 + j0 * 4 + 4);
    const float v = xT[k * B + b];
    az0 += w0.x * v; ar0 += w0.y * v; acx0 += w0.z * v;
    az1 += w1.x * v; ar1 += w1.y * v; acx1 += w1.z * v;
  }
  const int hs = max(k0, Kx);
#pragma unroll 4
  for (int k = hs; k < k1e; ++k) {
    const int kk = k - Kx;
    const float4 w0 = *reinterpret_cast<const float4*>(Whp + (size_t)kk * 1024 + j0 * 4);
    const float4 w1 = *reinterpret_cast<const float4*>(Whp + (size_t)kk * 1024 + j0 * 4 + 4);
    const float v = hT_old[kk * B + b];
    az0 += w0.x * v; ar0 += w0.y * v; ach0 += w0.z * v;
    az1 += w1.x * v; ar1 += w1.y * v; ach1 += w1.z * v;
  }
  float* pw = part + w16 * 512;
  pw[0 * 64 + lane] = az0;  pw[1 * 64 + lane] = ar0;
  pw[2 * 64 + lane] = acx0; pw[3 * 64 + lane] = ach0;
  pw[4 * 64 + lane] = az1;  pw[5 * 64 + lane] = ar1;
  pw[6 * 64 + lane] = acx1; pw[7 * 64 + lane] = ach1;
  __syncthreads();
  if (tid < 512) {
    float s = 0.f;
#pragma unroll
    for (int w = 0; w < 16; ++w) s += part[w * 512 + tid];
    red[tid] = s;
  }
  __syncthreads();
  if (tid < 128) {
    const int jp = tid >> 6, ln = tid & 63;
    const int j = j0 + jp;
    const int bb = bh * 64 + ln;
    const float az = red[(jp * 4 + 0) * 64 + ln];
    const float ar = red[(jp * 4 + 1) * 64 + ln];
    const float acx = red[(jp * 4 + 2) * 64 + ln];
    const float ach = red[(jp * 4 + 3) * 64 + ln];
    const float z = 1.f / (1.f + __expf(-(az + b3[j])));
    const float r = 1.f / (1.f + __expf(-(ar + b3[H + j])));
    const float carg = acx + r * ach + b3[2 * H + j];
    const float ex = __expf(2.f * carg);
    const float c = 1.f - 2.f / (ex + 1.f);
    const float hold = hT_old[j * B + bb];
    const float hn = (1.f - z) * hold + z * c;
    hT_new[j * B + bb] = hn;
    if (resOut) resOut[j * B + bb] = resIn[j * B + bb] + hn;
  }
}

// ---------------------------------------------------------------------------
// grid=B, 1024 threads (16 waves): qW (split-K), e-pass (t strided over waves),
// softmax, alpha write, context (t-chunk per wave + LDS combine).
__global__ __launch_bounds__(1024) void k3_attn(
    int t, const float* __restrict__ queryT, const float* __restrict__ Wq,
    const float* __restrict__ v_att, const float* __restrict__ keys,
    const float* __restrict__ mem, float* __restrict__ ctxT,
    float* __restrict__ alpha_out) {
  const int b = blockIdx.x;
  const int tid = threadIdx.x;
  const int lane = tid & 63, w16 = tid >> 6;
  __shared__ float qk[H];
  __shared__ float vvs[H];
  __shared__ float ee[TIN];
  __shared__ float qred[1024];
  __shared__ float pctx[16 * 256];
  __shared__ float sred[16];
  __shared__ float sbc[2];

  {                                    // qW[b,:] split-K 4-way
    const int kq = tid >> 8, col = tid & 255;
    float acc = 0.f;
    const int k0 = kq * 64;
#pragma unroll 4
    for (int i = 0; i < 64; ++i) {
      const int k = k0 + i;
      acc += queryT[k * B + b] * Wq[k * H + col];
    }
    qred[kq * 256 + col] = acc;
  }
  if (tid < H) vvs[tid] = v_att[tid];
  __syncthreads();
  if (tid < H) qk[tid] = qred[tid] + qred[256 + tid] + qred[512 + tid] + qred[768 + tid];
  __syncthreads();

  float qkr[4], vvr[4];
#pragma unroll
  for (int i = 0; i < 4; ++i) {
    qkr[i] = qk[lane + i * 64];
    vvr[i] = vvs[lane + i * 64];
  }

  // e-pass: 32 t's per wave
  const float* kb = keys + (size_t)b * H;
  for (int tt = w16; tt < TIN; tt += 16) {
    const float* kr = kb + (size_t)tt * (B * H);
    float s = 0.f;
#pragma unroll
    for (int i = 0; i < 4; ++i) {
      const float x = kr[lane + i * 64] + qkr[i];
      const float ex2 = __expf(2.f * x);
      s += vvr[i] * (1.f - 2.f / (ex2 + 1.f));
    }
#pragma unroll
    for (int m = 1; m < 64; m <<= 1) s += __shfl_xor(s, m);
    if (lane == 0) ee[tt] = s;
  }
  __syncthreads();

  // softmax over 512
  const float e = (tid < TIN) ? ee[tid] : -1e30f;
  float mx = e;
#pragma unroll
  for (int m = 1; m < 64; m <<= 1) mx = fmaxf(mx, __shfl_xor(mx, m));
  if (lane == 0) sred[w16] = mx;
  __syncthreads();
  if (tid == 0) {
    float g = sred[0];
    for (int w = 1; w < 16; ++w) g = fmaxf(g, sred[w]);
    sbc[0] = g;
  }
  __syncthreads();
  const float gm = sbc[0];
  const float ex = (tid < TIN) ? __expf(e - gm) : 0.f;
  if (tid < TIN) ee[tid] = ex;
  float sm = ex;
#pragma unroll
  for (int m = 1; m < 64; m <<= 1) sm += __shfl_xor(sm, m);
  if (lane == 0) sred[w16] = sm;
  __syncthreads();
  if (tid == 0) {
    float s = 0.f;
    for (int w = 0; w < 16; ++w) s += sred[w];
    sbc[1] = 1.f / s;
  }
  __syncthreads();
  const float inv = sbc[1];
  if (tid < TIN) alpha_out[((size_t)t * B + b) * TIN + tid] = ex * inv;

  // context: 32 t's per wave, 4 k-regs per lane
  float acc[4] = {0.f, 0.f, 0.f, 0.f};
  const float* mb = mem + (size_t)b * H;
  const int t0 = w16 * 32;
#pragma unroll 2
  for (int i2 = 0; i2 < 32; ++i2) {
    const int tt = t0 + i2;
    const float p = ee[tt];
    const float* mr = mb + (size_t)tt * (B * H);
#pragma unroll
    for (int i = 0; i < 4; ++i) acc[i] += p * mr[lane + i * 64];
  }
#pragma unroll
  for (int i = 0; i < 4; ++i) pctx[w16 * 256 + i * 64 + lane] = acc[i];
  __syncthreads();
  if (tid < H) {
    float s = 0.f;
#pragma unroll
    for (int w = 0; w < 16; ++w) s += pctx[w * 256 + tid];
    ctxT[tid * B + b] = s * inv;
  }
}

// ---------------------------------------------------------------------------
extern "C" void kernel_launch(void* const* d_in, const int* in_sizes, int n_in,
                              void* d_out, int out_size, void* d_ws,
                              size_t ws_size, hipStream_t stream) {
  const float* outs   = (const float*)d_in[0];
  const float* memory = (const float*)d_in[1];
  const float* Wp0    = (const float*)d_in[2];
  const float* bp0    = (const float*)d_in[3];
  const float* Wp1    = (const float*)d_in[4];
  const float* bp1    = (const float*)d_in[5];
  const float* Wx_att = (const float*)d_in[6];
  const float* Wh_att = (const float*)d_in[7];
  const float* b_att  = (const float*)d_in[8];
  const float* Wq     = (const float*)d_in[9];
  const float* Wm     = (const float*)d_in[10];
  const float* v_att  = (const float*)d_in[11];
  const float* Wx_d0  = (const float*)d_in[12];
  const float* Wh_d0  = (const float*)d_in[13];
  const float* b_d0   = (const float*)d_in[14];
  const float* Wx_d1  = (const float*)d_in[15];
  const float* Wh_d1  = (const float*)d_in[16];
  const float* b_d1   = (const float*)d_in[17];
  const float* Wo     = (const float*)d_in[18];
  const float* bo     = (const float*)d_in[19];
  float* dout = (float*)d_out;
  float* wsf  = (float*)d_ws;

  size_t off = 0;
  float* keys    = wsf + off; off += (size_t)TIN * B * H;
  float* wxp_att = wsf + off; off += (size_t)128 * 1024;
  float* whp_att = wsf + off; off += (size_t)256 * 1024;
  float* wxp_d0  = wsf + off; off += (size_t)512 * 1024;
  float* whp_d0  = wsf + off; off += (size_t)256 * 1024;
  float* wxp_d1  = wsf + off; off += (size_t)256 * 1024;
  float* whp_d1  = wsf + off; off += (size_t)256 * 1024;
  float* xcat[2];
  xcat[0] = wsf + off; off += (size_t)2 * H * B;
  xcat[1] = wsf + off; off += (size_t)2 * H * B;
  float* hd0[2];
  hd0[0] = wsf + off; off += (size_t)H * B;
  hd0[1] = wsf + off; off += (size_t)H * B;
  float* hd1[2];
  hd1[0] = wsf + off; off += (size_t)H * B;
  hd1[1] = wsf + off; off += (size_t)H * B;
  float* preT = wsf + off; off += (size_t)PP * B;
  float* res0 = wsf + off; off += (size_t)H * B;
  float* res1 = wsf + off; off += (size_t)H * B;

  hipMemsetAsync(xcat[0], 0, (size_t)H * B * sizeof(float), stream);
  hipMemsetAsync(hd0[0], 0, (size_t)H * B * sizeof(float), stream);
  hipMemsetAsync(hd1[0], 0, (size_t)H * B * sizeof(float), stream);

  k_keys<<<(TIN * B) / 32, 256, 0, stream>>>(memory, Wm, keys);
  k_pack<<<(128 * H3 + 255) / 256, 256, 0, stream>>>(Wx_att, wxp_att, 128);
  k_pack<<<(256 * H3 + 255) / 256, 256, 0, stream>>>(Wh_att, whp_att, 256);
  k_pack<<<(512 * H3 + 255) / 256, 256, 0, stream>>>(Wx_d0, wxp_d0, 512);
  k_pack<<<(256 * H3 + 255) / 256, 256, 0, stream>>>(Wh_d0, whp_d0, 256);
  k_pack<<<(256 * H3 + 255) / 256, 256, 0, stream>>>(Wx_d1, wxp_d1, 256);
  k_pack<<<(256 * H3 + 255) / 256, 256, 0, stream>>>(Wh_d1, whp_d1, 256);

  float* alpha_out = dout + (size_t)1000 * B * D;

  for (int t = 0; t < RSTEPS; ++t) {
    const int pi = t & 1, po = 1 - pi;
    k1_dense_prenet<<<B, 512, 0, stream>>>(t, outs, res1, Wo, bo, Wp0, bp0,
                                           Wp1, bp1, preT, dout);
    k_gru<<<256, 1024, 0, stream>>>(preT, PP, wxp_att, xcat[pi], whp_att,
                                    b_att, xcat[po], nullptr, nullptr);
    k3_attn<<<B, 1024, 0, stream>>>(t, xcat[po], Wq, v_att, keys, memory,
                                    xcat[po] + (size_t)H * B, alpha_out);
    k_gru<<<256, 1024, 0, stream>>>(xcat[po], 2 * H, wxp_d0, hd0[pi], whp_d0,
                                    b_d0, hd0[po], xcat[po], res0);
    k_gru<<<256, 1024, 0, stream>>>(res0, H, wxp_d1, hd1[pi], whp_d1, b_d1,
                                    hd1[po], res0, res1);
  }
  k1_dense_prenet<<<B, 512, 0, stream>>>(RSTEPS, outs, res1, Wo, bo, Wp0, bp0,
                                         Wp1, bp1, preT, dout);
}